// Round 1
// baseline (721.548 us; speedup 1.0000x reference)
//
#include <hip/hip_runtime.h>
#include <hip/hip_bf16.h>

// Problem constants (match reference: shape=[15,400,400], batch_size=2)
#define DD 15
#define HH 400
#define WW 400
#define CIN 32
#define COUT 64
#define KK 27

// ---------------- flats: flat voxel index per active voxel (sorted by construction) ----
__global__ void build_flats_kernel(const int* __restrict__ coors,
                                   int* __restrict__ flats, int n) {
    int i = blockIdx.x * blockDim.x + threadIdx.x;
    if (i >= n) return;
    int b = coors[i * 4 + 0];
    int z = coors[i * 4 + 1];
    int y = coors[i * 4 + 2];
    int x = coors[i * 4 + 3];
    flats[i] = ((b * DD + z) * HH + y) * WW + x;
}

// ---------------- rulebook: nbr[i][k] = row index of neighbor, -1 if inactive ---------
__global__ void build_nbr_kernel(const int* __restrict__ coors,
                                 const int* __restrict__ flats,
                                 int* __restrict__ nbr, int n) {
    int t = blockIdx.x * blockDim.x + threadIdx.x;
    if (t >= n * KK) return;
    int i = t / KK;
    int k = t - i * KK;               // k fast: 27 consecutive threads share a voxel
    int dz = k / 9 - 1;
    int dy = (k / 3) % 3 - 1;
    int dx = k % 3 - 1;
    int b = coors[i * 4 + 0];
    int z = coors[i * 4 + 1] + dz;
    int y = coors[i * 4 + 2] + dy;
    int x = coors[i * 4 + 3] + dx;
    int j = -1;
    if (z >= 0 && z < DD && y >= 0 && y < HH && x >= 0 && x < WW) {
        int target = ((b * DD + z) * HH + y) * WW + x;
        // binary search in sorted unique flats[0..n)
        int lo = 0, hi = n - 1;
        while (lo <= hi) {
            int mid = (lo + hi) >> 1;
            int v = flats[mid];
            if (v < target) lo = mid + 1;
            else if (v > target) hi = mid - 1;
            else { j = mid; break; }
        }
    }
    nbr[i * KK + k] = j;
}

// ---------------- layer 1: fp32 features [N,32] -> bf16 x [N,64] ----------------------
// one wave (64 lanes) per voxel; lane = output channel
__global__ __launch_bounds__(256) void conv1_kernel(
        const float* __restrict__ feats, const int* __restrict__ nbr,
        const float* __restrict__ W1, __hip_bfloat16* __restrict__ xout, int n) {
    int lane = threadIdx.x & 63;
    int i = blockIdx.x * 4 + (threadIdx.x >> 6);
    if (i >= n) return;
    const int* nb = nbr + (size_t)i * KK;
    float acc = 0.f;
    for (int k = 0; k < KK; ++k) {
        int j = nb[k];                 // wave-uniform -> coherent skip
        if (j < 0) continue;
        const float* fr = feats + (size_t)j * CIN;
        const float* wk = W1 + (size_t)k * CIN * COUT + lane;
#pragma unroll
        for (int c = 0; c < CIN; ++c)
            acc += fr[c] * wk[c * COUT];
    }
    xout[(size_t)i * COUT + lane] = __float2bfloat16(acc);
}

// ---------------- layer 2: bf16 x [N,64] -> fp32 out [N,64] ---------------------------
__global__ __launch_bounds__(256) void conv2_kernel(
        const __hip_bfloat16* __restrict__ xin, const int* __restrict__ nbr,
        const float* __restrict__ W2, float* __restrict__ out, int n) {
    int lane = threadIdx.x & 63;
    int i = blockIdx.x * 4 + (threadIdx.x >> 6);
    if (i >= n) return;
    const int* nb = nbr + (size_t)i * KK;
    float acc = 0.f;
    for (int k = 0; k < KK; ++k) {
        int j = nb[k];
        if (j < 0) continue;
        const __hip_bfloat16* fr = xin + (size_t)j * COUT;
        const float* wk = W2 + (size_t)k * COUT * COUT + lane;
#pragma unroll
        for (int c = 0; c < COUT; ++c)
            acc += __bfloat162float(fr[c]) * wk[c * COUT];
    }
    out[(size_t)i * COUT + lane] = acc;
}

extern "C" void kernel_launch(void* const* d_in, const int* in_sizes, int n_in,
                              void* d_out, int out_size, void* d_ws, size_t ws_size,
                              hipStream_t stream) {
    const float* feats = (const float*)d_in[0];   // [N,32] fp32
    const int*   coors = (const int*)d_in[1];     // [N,4] int32
    // d_in[2] = batch_size (scalar, constant 2) -- folded into DD/HH/WW arithmetic
    const float* W1 = (const float*)d_in[3];      // [27,32,64] fp32
    const float* W2 = (const float*)d_in[4];      // [27,64,64] fp32
    float* out = (float*)d_out;                   // [N,64] fp32

    int n = in_sizes[0] / CIN;                    // 200000

    // workspace layout (all 256B-aligned): flats | nbr | x(bf16)   total ~48 MB
    char* ws = (char*)d_ws;
    size_t off = 0;
    int* flats = (int*)(ws + off);
    off += ((size_t)n * 4 + 255) & ~(size_t)255;
    int* nbr = (int*)(ws + off);
    off += ((size_t)n * KK * 4 + 255) & ~(size_t)255;
    __hip_bfloat16* x = (__hip_bfloat16*)(ws + off);

    build_flats_kernel<<<(n + 255) / 256, 256, 0, stream>>>(coors, flats, n);
    build_nbr_kernel<<<((n * KK) + 255) / 256, 256, 0, stream>>>(coors, flats, nbr, n);
    conv1_kernel<<<(n + 3) / 4, 256, 0, stream>>>(feats, nbr, W1, x, n);
    conv2_kernel<<<(n + 3) / 4, 256, 0, stream>>>(x, nbr, W2, out, n);
}

// Round 2
// 626.688 us; speedup vs baseline: 1.1514x; 1.1514x over previous
//
#include <hip/hip_runtime.h>
#include <hip/hip_bf16.h>

// Problem constants (match reference: shape=[15,400,400], batch_size=2)
#define DD 15
#define HH 400
#define WW 400
#define CIN 32
#define COUT 64
#define KK 27

__device__ inline float bflo(unsigned u) {            // low bf16 of packed pair -> f32
    return __uint_as_float(u << 16);
}
__device__ inline float bfhi(unsigned u) {            // high bf16 -> f32
    return __uint_as_float(u & 0xFFFF0000u);
}
__device__ inline unsigned short f2bf(float f) {      // f32 -> bf16 RNE
    unsigned u = __float_as_uint(f);
    return (unsigned short)((u + 0x7FFFu + ((u >> 16) & 1u)) >> 16);
}

// ---------------- flats: flat voxel index per active voxel (sorted by construction) ----
__global__ void build_flats_kernel(const int* __restrict__ coors,
                                   int* __restrict__ flats, int n) {
    int i = blockIdx.x * blockDim.x + threadIdx.x;
    if (i >= n) return;
    int b = coors[i * 4 + 0];
    int z = coors[i * 4 + 1];
    int y = coors[i * 4 + 2];
    int x = coors[i * 4 + 3];
    flats[i] = ((b * DD + z) * HH + y) * WW + x;
}

// ---------------- rulebook: one lower_bound per (dz,dy) covers dx=-1,0,1 --------------
__global__ void build_nbr9_kernel(const int* __restrict__ coors,
                                  const int* __restrict__ flats,
                                  int* __restrict__ nbr, int n) {
    int t = blockIdx.x * blockDim.x + threadIdx.x;
    if (t >= n * 9) return;
    int i = t / 9;
    int p = t - i * 9;                 // (dz+1)*3 + (dy+1)
    int dz = p / 3 - 1;
    int dy = p % 3 - 1;
    int b = coors[i * 4 + 0];
    int z = coors[i * 4 + 1] + dz;
    int y = coors[i * 4 + 2] + dy;
    int x = coors[i * 4 + 3];
    int j0 = -1, j1 = -1, j2 = -1;
    if (z >= 0 && z < DD && y >= 0 && y < HH) {
        int tmid = ((b * DD + z) * HH + y) * WW + x;   // dx = 0 target
        int tlo = tmid - 1;
        // lower_bound(tlo)
        int lo = 0, hi = n;
        while (lo < hi) {
            int mid = (lo + hi) >> 1;
            if (flats[mid] < tlo) lo = mid + 1; else hi = mid;
        }
#pragma unroll
        for (int s = 0; s < 3; ++s) {
            int idx = lo + s;
            if (idx < n) {
                int d = flats[idx] - tlo;              // 0,1,2 -> dx=-1,0,+1
                if (d == 0) j0 = idx;
                else if (d == 1) j1 = idx;
                else if (d == 2) j2 = idx;
            }
        }
        if (x == 0) j0 = -1;                           // x-1 out of range
        if (x == WW - 1) j2 = -1;                      // x+1 out of range
    }
    int base = t * 3;                                  // == i*27 + p*3
    nbr[base + 0] = j0;
    nbr[base + 1] = j1;
    nbr[base + 2] = j2;
}

// ---------------- layer 1: fp32 feats [N,32] -> bf16 x [N,64] -------------------------
// one wave per voxel; 4 groups x 16 lanes; group g: c in [g*8, g*8+8);
// lane-in-group lg: couts [lg*4, lg*4+4) via float4 weight loads.
__global__ __launch_bounds__(256) void conv1_kernel(
        const float* __restrict__ feats, const int* __restrict__ nbr,
        const float* __restrict__ W1, __hip_bfloat16* __restrict__ xout, int n) {
    int lane = threadIdx.x & 63;
    int g = lane >> 4;
    int lg = lane & 15;
    int i = blockIdx.x * 4 + (threadIdx.x >> 6);
    if (i >= n) return;
    const int* nb = nbr + (size_t)i * KK;
    float4 acc = make_float4(0.f, 0.f, 0.f, 0.f);
    for (int k = 0; k < KK; ++k) {
        int j = nb[k];                                 // wave-uniform
        if (j < 0) continue;
        const float4* fp = (const float4*)(feats + (size_t)j * CIN + g * 8);
        float4 f0 = fp[0], f1 = fp[1];                 // 8 fp32 (broadcast in group)
        const float4* wb = (const float4*)(W1 + (size_t)k * CIN * COUT) + (size_t)(g * 8) * 16 + lg;
        float fr[8] = {f0.x, f0.y, f0.z, f0.w, f1.x, f1.y, f1.z, f1.w};
#pragma unroll
        for (int c = 0; c < 8; ++c) {
            float4 w = wb[c * 16];                     // 16B/lane, contiguous per group
            acc.x += fr[c] * w.x;
            acc.y += fr[c] * w.y;
            acc.z += fr[c] * w.z;
            acc.w += fr[c] * w.w;
        }
    }
    // reduce across the 4 c-groups (lanes l, l^16, l^32)
    acc.x += __shfl_xor(acc.x, 16); acc.y += __shfl_xor(acc.y, 16);
    acc.z += __shfl_xor(acc.z, 16); acc.w += __shfl_xor(acc.w, 16);
    acc.x += __shfl_xor(acc.x, 32); acc.y += __shfl_xor(acc.y, 32);
    acc.z += __shfl_xor(acc.z, 32); acc.w += __shfl_xor(acc.w, 32);
    if (g == 0) {                                      // lanes 0..15 store 4 bf16 each
        uint2 pk;
        pk.x = (unsigned)f2bf(acc.x) | ((unsigned)f2bf(acc.y) << 16);
        pk.y = (unsigned)f2bf(acc.z) | ((unsigned)f2bf(acc.w) << 16);
        *(uint2*)((unsigned short*)xout + (size_t)i * COUT + lg * 4) = pk;
    }
}

// ---------------- layer 2: bf16 x [N,64] -> fp32 out [N,64] ---------------------------
// group g: c in [g*16, g*16+16); lane-in-group lg: couts [lg*4, lg*4+4).
__global__ __launch_bounds__(256) void conv2_kernel(
        const __hip_bfloat16* __restrict__ xin, const int* __restrict__ nbr,
        const float* __restrict__ W2, float* __restrict__ out, int n) {
    int lane = threadIdx.x & 63;
    int g = lane >> 4;
    int lg = lane & 15;
    int i = blockIdx.x * 4 + (threadIdx.x >> 6);
    if (i >= n) return;
    const int* nb = nbr + (size_t)i * KK;
    float4 acc = make_float4(0.f, 0.f, 0.f, 0.f);
    for (int k = 0; k < KK; ++k) {
        int j = nb[k];                                 // wave-uniform
        if (j < 0) continue;
        const uint4* xp = (const uint4*)((const unsigned short*)xin + (size_t)j * COUT + g * 16);
        uint4 q0 = xp[0], q1 = xp[1];                  // 16 bf16 (broadcast in group)
        float fr[16] = {
            bflo(q0.x), bfhi(q0.x), bflo(q0.y), bfhi(q0.y),
            bflo(q0.z), bfhi(q0.z), bflo(q0.w), bfhi(q0.w),
            bflo(q1.x), bfhi(q1.x), bflo(q1.y), bfhi(q1.y),
            bflo(q1.z), bfhi(q1.z), bflo(q1.w), bfhi(q1.w)};
        const float4* wb = (const float4*)(W2 + (size_t)k * COUT * COUT) + (size_t)(g * 16) * 16 + lg;
#pragma unroll
        for (int c = 0; c < 16; ++c) {
            float4 w = wb[c * 16];
            acc.x += fr[c] * w.x;
            acc.y += fr[c] * w.y;
            acc.z += fr[c] * w.z;
            acc.w += fr[c] * w.w;
        }
    }
    acc.x += __shfl_xor(acc.x, 16); acc.y += __shfl_xor(acc.y, 16);
    acc.z += __shfl_xor(acc.z, 16); acc.w += __shfl_xor(acc.w, 16);
    acc.x += __shfl_xor(acc.x, 32); acc.y += __shfl_xor(acc.y, 32);
    acc.z += __shfl_xor(acc.z, 32); acc.w += __shfl_xor(acc.w, 32);
    if (g == 0) {
        *(float4*)(out + (size_t)i * COUT + lg * 4) = acc;
    }
}

extern "C" void kernel_launch(void* const* d_in, const int* in_sizes, int n_in,
                              void* d_out, int out_size, void* d_ws, size_t ws_size,
                              hipStream_t stream) {
    const float* feats = (const float*)d_in[0];   // [N,32] fp32
    const int*   coors = (const int*)d_in[1];     // [N,4] int32
    const float* W1 = (const float*)d_in[3];      // [27,32,64] fp32
    const float* W2 = (const float*)d_in[4];      // [27,64,64] fp32
    float* out = (float*)d_out;                   // [N,64] fp32

    int n = in_sizes[0] / CIN;                    // 200000

    // workspace layout: flats | nbr | x(bf16)   total ~48 MB
    char* ws = (char*)d_ws;
    size_t off = 0;
    int* flats = (int*)(ws + off);
    off += ((size_t)n * 4 + 255) & ~(size_t)255;
    int* nbr = (int*)(ws + off);
    off += ((size_t)n * KK * 4 + 255) & ~(size_t)255;
    __hip_bfloat16* x = (__hip_bfloat16*)(ws + off);

    build_flats_kernel<<<(n + 255) / 256, 256, 0, stream>>>(coors, flats, n);
    build_nbr9_kernel<<<((n * 9) + 255) / 256, 256, 0, stream>>>(coors, flats, nbr, n);
    conv1_kernel<<<(n + 3) / 4, 256, 0, stream>>>(feats, nbr, W1, x, n);
    conv2_kernel<<<(n + 3) / 4, 256, 0, stream>>>(x, nbr, W2, out, n);
}